// Round 7
// baseline (518.337 us; speedup 1.0000x reference)
//
#include <hip/hip_runtime.h>

#define TT 64
#define NN 512
#define DD 128

typedef __attribute__((ext_vector_type(8))) short bf16x8;
typedef __attribute__((ext_vector_type(4))) float f32x4;

__device__ __forceinline__ unsigned short f2bf(float f) {
  unsigned int u = __float_as_uint(f);
  u += 0x7fffu + ((u >> 16) & 1u);          // RNE
  return (unsigned short)(u >> 16);
}

__device__ __forceinline__ unsigned cvtpk(float lo, float hi) {
  unsigned r;
  asm("v_cvt_pk_bf16_f32 %0, %1, %2" : "=v"(r) : "v"(lo), "v"(hi));
  return r;
}

// XOR-swizzled LDS index helpers (units: unsigned short elements).
__device__ __forceinline__ int swz128(int row, int col) {
  return row * 128 + (((col >> 3) ^ (row & 15)) << 3) + (col & 7);
}
__device__ __forceinline__ int swz64(int row, int col) {
  return row * 64 + (((col >> 3) ^ (row & 7)) << 3) + (col & 7);
}

// Barrier with LDS-only drain: global loads stay in flight across it.
__device__ __forceinline__ void bar() {
  asm volatile("s_waitcnt lgkmcnt(0)" ::: "memory");
  __builtin_amdgcn_s_barrier();
  asm volatile("" ::: "memory");
}

// 16-lane (DPP-row) sum via row_ror butterflies — VALU pipe, no LDS traffic.
__device__ __forceinline__ float red16(float s) {
  int t;
  t = __builtin_amdgcn_update_dpp(0, __float_as_int(s), 0x121, 0xf, 0xf, false);
  s += __int_as_float(t);
  t = __builtin_amdgcn_update_dpp(0, __float_as_int(s), 0x122, 0xf, 0xf, false);
  s += __int_as_float(t);
  t = __builtin_amdgcn_update_dpp(0, __float_as_int(s), 0x124, 0xf, 0xf, false);
  s += __int_as_float(t);
  t = __builtin_amdgcn_update_dpp(0, __float_as_int(s), 0x128, 0xf, 0xf, false);
  s += __int_as_float(t);
  return s;
}

// Prefetch kk=0 B-fragments (issued a stage early; survive lgkm barriers).
template<int KDIM>
__device__ __forceinline__ void pf_b1(const unsigned short* __restrict__ Bg, int c0,
                                      int li, int lg, bf16x8 pre[4]) {
  #pragma unroll
  for (int ct = 0; ct < 4; ++ct)
    pre[ct] = *(const bf16x8*)(Bg + (c0 + ct * 16 + li) * KDIM + lg * 8);
}

template<int KDIM>
__device__ __forceinline__ void gemm4_pre(const bf16x8* af, const unsigned short* __restrict__ Bg,
                                          int c0, f32x4 acc[4], int li, int lg,
                                          const bf16x8 pre[4]) {
  #pragma unroll
  for (int kk = 0; kk < KDIM / 32; ++kk) {
    #pragma unroll
    for (int ct = 0; ct < 4; ++ct) {
      bf16x8 bfr;
      if (kk == 0) bfr = pre[ct];
      else bfr = *(const bf16x8*)(Bg + (c0 + ct * 16 + li) * KDIM + kk * 32 + lg * 8);
      acc[ct] = __builtin_amdgcn_mfma_f32_16x16x32_bf16(af[kk], bfr, acc[ct], 0, 0, 0);
    }
  }
}

template<int NFR>
__device__ __forceinline__ void load_af128(const unsigned short* As, int row, bf16x8* af, int lg) {
  #pragma unroll
  for (int kk = 0; kk < NFR; ++kk)
    af[kk] = *(const bf16x8*)(As + swz128(row, kk * 32 + lg * 8));
}

__device__ __forceinline__ void epi4(const f32x4 acc[4], const float* __restrict__ bias,
                                     unsigned short* dst, bool relu,
                                     int li, int lg, int q0, int c0) {
  #pragma unroll
  for (int ct = 0; ct < 4; ++ct) {
    float bv = bias[c0 + ct * 16 + li];
    #pragma unroll
    for (int r = 0; r < 4; ++r) {
      float v = acc[ct][r] + bv;
      if (relu) v = fmaxf(v, 0.0f);
      dst[swz128(q0 + lg * 4 + r, c0 + ct * 16 + li)] = f2bf(v);
    }
  }
}

// transpose fp32 [K][N] -> bf16 [N][K]
__global__ void wprep(const float* __restrict__ src, unsigned short* __restrict__ dst,
                      int K, int Nn) {
  int idx = blockIdx.x * 256 + threadIdx.x;
  if (idx >= K * Nn) return;
  int n = idx / K, k = idx - n * K;
  dst[idx] = f2bf(src[k * Nn + n]);
}

#define KSCL 0.36067376022224085f   // 0.25 * log2(e), folded into K epilogue

__global__ __launch_bounds__(512, 6)
void fused_layer(const float* __restrict__ x_in, const float* __restrict__ ste,
                 const float* __restrict__ g1, const float* __restrict__ b1,
                 const float* __restrict__ g2, const float* __restrict__ b2,
                 const unsigned short* __restrict__ wqt, const float* __restrict__ bq,
                 const unsigned short* __restrict__ wkt, const float* __restrict__ bk,
                 const unsigned short* __restrict__ wvt, const float* __restrict__ bv,
                 const unsigned short* __restrict__ wo1t, const float* __restrict__ bo1,
                 const unsigned short* __restrict__ wo2t, const float* __restrict__ bo2,
                 const unsigned short* __restrict__ wf1t, const float* __restrict__ bf1,
                 const unsigned short* __restrict__ wf2t, const float* __restrict__ bf2,
                 float* __restrict__ out) {
  __shared__ __align__(16) unsigned short smem[25088];  // 49 KB

  const int tid = threadIdx.x;
  const int lane = tid & 63;
  const int w  = tid >> 6;         // wave 0..7
  const int wr = w >> 1;           // row group (rows 16wr..16wr+15)
  const int wc = w & 1;            // col half
  const int lg = lane >> 4;        // 0..3
  const int li = lane & 15;
  const int q0 = wr * 16;
  const int c0 = wc * 64;

  const int blk = blockIdx.x;
  const int b = blk >> 9;          // N=512
  const int n = blk & 511;
  const int rs = NN * DD;
  const float* xbase = x_in + (b * TT * NN + n) * DD;
  const float* sbase = ste + (b * TT * NN + n) * DD;

  // Region plan (lifetimes guarded by barriers):
  //  [0..16384)      X2s [64][256] bf16 (xnorm|STE), dead after B0e
  //  [0..8192)       post-B0e: Qb [64][128] (Q, then AO strips)   | post-B5: Hf
  //  [8192..16384)   post-B0e: Kb [64][128]                       | post-B2: H1
  //  [16384..24576)  Vt [128][64] (V^T)                           | post-B4: Xn2
  //  [24576..25088)  lnpf (LN2 partials, 1KB)
  unsigned short* X2s = smem;
  unsigned short* Qb  = smem;
  unsigned short* Kb  = smem + 8192;
  unsigned short* Vt  = smem + 16384;
  unsigned short* H1  = smem + 8192;
  unsigned short* Xn2 = smem + 16384;
  unsigned short* Hf  = smem;
  float* lnpf = (float*)(smem + 24576);

  #define SWZ256(row, col) ((row) * 256 + ((((col) >> 3) ^ ((row) & 15)) << 3) + ((col) & 7))

  // ---------------- LN1 + STE -> X2 (16 lanes per row; rows w*8..w*8+7) ----
  {
    float4 gA = *(const float4*)(g1 + li * 8);
    float4 gB = *(const float4*)(g1 + li * 8 + 4);
    float4 bA = *(const float4*)(b1 + li * 8);
    float4 bB = *(const float4*)(b1 + li * 8 + 4);
    #pragma unroll
    for (int pass = 0; pass < 2; ++pass) {
      int t = w * 8 + pass * 4 + lg;
      float4 xA = *(const float4*)(xbase + t * rs + li * 8);
      float4 xB = *(const float4*)(xbase + t * rs + li * 8 + 4);
      float s1 = xA.x + xA.y + xA.z + xA.w + xB.x + xB.y + xB.z + xB.w;
      float s2 = xA.x * xA.x + xA.y * xA.y + xA.z * xA.z + xA.w * xA.w +
                 xB.x * xB.x + xB.y * xB.y + xB.z * xB.z + xB.w * xB.w;
      s1 = red16(s1);
      s2 = red16(s2);
      float mean = s1 * (1.0f / 128.0f);
      float var = fmaxf((s2 - s1 * mean) * (1.0f / 127.0f), 0.0f);  // ddof=1
      float inv = 1.0f / (sqrtf(var) + 1e-6f);
      bf16x8 o;
      o[0] = (short)f2bf(gA.x * (xA.x - mean) * inv + bA.x);
      o[1] = (short)f2bf(gA.y * (xA.y - mean) * inv + bA.y);
      o[2] = (short)f2bf(gA.z * (xA.z - mean) * inv + bA.z);
      o[3] = (short)f2bf(gA.w * (xA.w - mean) * inv + bA.w);
      o[4] = (short)f2bf(gB.x * (xB.x - mean) * inv + bB.x);
      o[5] = (short)f2bf(gB.y * (xB.y - mean) * inv + bB.y);
      o[6] = (short)f2bf(gB.z * (xB.z - mean) * inv + bB.z);
      o[7] = (short)f2bf(gB.w * (xB.w - mean) * inv + bB.w);
      *(bf16x8*)(X2s + SWZ256(t, li * 8)) = o;
      float4 sA = *(const float4*)(sbase + t * rs + li * 8);
      float4 sB = *(const float4*)(sbase + t * rs + li * 8 + 4);
      bf16x8 so;
      so[0] = (short)f2bf(sA.x); so[1] = (short)f2bf(sA.y);
      so[2] = (short)f2bf(sA.z); so[3] = (short)f2bf(sA.w);
      so[4] = (short)f2bf(sB.x); so[5] = (short)f2bf(sB.y);
      so[6] = (short)f2bf(sB.z); so[7] = (short)f2bf(sB.w);
      *(bf16x8*)(X2s + SWZ256(t, 128 + li * 8)) = so;
    }
  }

  // K/V column-strip assignment: wave w<4 -> K cols 32w..32w+31, w>=4 -> V cols.
  const unsigned short* kvB;
  const float* kvbias;
  if (w < 4) { kvB = wkt + (w * 32) * 256;        kvbias = bk + w * 32; }
  else       { kvB = wvt + ((w - 4) * 32) * 256;  kvbias = bv + (w - 4) * 32; }

  bar();  // B0: X2 visible

  // ---------------- K/V projections (col-strip: all 64 rows, 32 cols) -----
  f32x4 kv[4][2];
  #pragma unroll
  for (int rg = 0; rg < 4; ++rg)
    #pragma unroll
    for (int ct = 0; ct < 2; ++ct) kv[rg][ct] = (f32x4){0, 0, 0, 0};
  #pragma unroll
  for (int kk = 0; kk < 8; ++kk) {
    bf16x8 bc[2];
    #pragma unroll
    for (int ct = 0; ct < 2; ++ct)
      bc[ct] = *(const bf16x8*)(kvB + (ct * 16 + li) * 256 + kk * 32 + lg * 8);
    #pragma unroll
    for (int rg = 0; rg < 4; ++rg) {
      bf16x8 af = *(const bf16x8*)(X2s + SWZ256(rg * 16 + li, kk * 32 + lg * 8));
      #pragma unroll
      for (int ct = 0; ct < 2; ++ct)
        kv[rg][ct] = __builtin_amdgcn_mfma_f32_16x16x32_bf16(af, bc[ct], kv[rg][ct], 0, 0, 0);
    }
  }

  // ---------------- Q projection (own 16 rows x 64-col half) --------------
  f32x4 qacc[4];
  #pragma unroll
  for (int i = 0; i < 4; ++i) qacc[i] = (f32x4){0, 0, 0, 0};
  #pragma unroll
  for (int kk = 0; kk < 8; ++kk) {
    bf16x8 af = *(const bf16x8*)(X2s + SWZ256(q0 + li, kk * 32 + lg * 8));
    #pragma unroll
    for (int ct = 0; ct < 4; ++ct)
      qacc[ct] = __builtin_amdgcn_mfma_f32_16x16x32_bf16(
          af, *(const bf16x8*)(wqt + (c0 + ct * 16 + li) * 256 + kk * 32 + lg * 8),
          qacc[ct], 0, 0, 0);
  }

  bar();  // B0e: ALL X2 reads done -> X2 region reusable for Kb/Qb

  // K (scaled by 0.25*log2e), V^T, Q epilogues into overlay regions
  if (w < 4) {
    #pragma unroll
    for (int ct = 0; ct < 2; ++ct) {
      float bvv = kvbias[ct * 16 + li];
      #pragma unroll
      for (int rg = 0; rg < 4; ++rg)
        #pragma unroll
        for (int r = 0; r < 4; ++r)
          Kb[swz128(rg * 16 + lg * 4 + r, w * 32 + ct * 16 + li)] =
              f2bf(fmaxf(kv[rg][ct][r] + bvv, 0.0f) * KSCL);
    }
  } else {
    #pragma unroll
    for (int ct = 0; ct < 2; ++ct) {
      float bvv = kvbias[ct * 16 + li];
      int d = (w - 4) * 32 + ct * 16 + li;
      #pragma unroll
      for (int rg = 0; rg < 4; ++rg) {
        float v0 = fmaxf(kv[rg][ct][0] + bvv, 0.0f);
        float v1 = fmaxf(kv[rg][ct][1] + bvv, 0.0f);
        float v2 = fmaxf(kv[rg][ct][2] + bvv, 0.0f);
        float v3 = fmaxf(kv[rg][ct][3] + bvv, 0.0f);
        uint2 pv; pv.x = cvtpk(v0, v1); pv.y = cvtpk(v2, v3);
        *(uint2*)(Vt + swz64(d, rg * 16 + lg * 4)) = pv;   // 8B aligned
      }
    }
  }
  epi4(qacc, bq, Qb, true, li, lg, q0, c0);

  bar();  // B1: Kb/Vt/Qb visible everywhere

  // ---------------- causal attention, head-major (wave w = head w) --------
  {
    const int hc = w * 16;
    const bf16x8 zf = (bf16x8){0, 0, 0, 0, 0, 0, 0, 0};
    bf16x8 kf[4], vf[2];
    #pragma unroll
    for (int pt = 0; pt < 4; ++pt)
      kf[pt] = (lg < 2) ? *(const bf16x8*)(Kb + swz128(pt * 16 + li, hc + lg * 8)) : zf;
    #pragma unroll
    for (int ks = 0; ks < 2; ++ks)
      vf[ks] = *(const bf16x8*)(Vt + swz64(hc + li, ks * 32 + lg * 8));

    #pragma unroll
    for (int qt = 0; qt < 4; ++qt) {
      bf16x8 qf = (lg < 2) ? *(const bf16x8*)(Qb + swz128(qt * 16 + li, hc + lg * 8)) : zf;
      f32x4 st[4];
      #pragma unroll
      for (int pt = 0; pt < 4; ++pt)
        if (pt <= qt)   // compile-time after unroll: causal tile skip
          st[pt] = __builtin_amdgcn_mfma_f32_16x16x32_bf16(kf[pt], qf, (f32x4){0, 0, 0, 0}, 0, 0, 0);

      // exp (scale pre-folded into K); pack P^T pairs; row-sum (q = qt*16+li)
      float ssum = 0.0f;
      unsigned pa[4], pb[4];
      #pragma unroll
      for (int pt = 0; pt < 4; ++pt) {
        if (pt > qt) { pa[pt] = 0; pb[pt] = 0; continue; }
        float e0 = exp2f(st[pt][0]);
        float e1 = exp2f(st[pt][1]);
        float e2 = exp2f(st[pt][2]);
        float e3 = exp2f(st[pt][3]);
        if (pt == qt) {  // diagonal tile: mask p_local > q_local
          e0 = (4 * lg + 0 > li) ? 0.0f : e0;
          e1 = (4 * lg + 1 > li) ? 0.0f : e1;
          e2 = (4 * lg + 2 > li) ? 0.0f : e2;
          e3 = (4 * lg + 3 > li) ? 0.0f : e3;
        }
        ssum += e0 + e1 + e2 + e3;
        pa[pt] = cvtpk(e0, e1);
        pb[pt] = cvtpk(e2, e3);
      }
      ssum += __shfl_xor(ssum, 16, 64);
      ssum += __shfl_xor(ssum, 32, 64);
      float rinv = 1.0f / ssum;

      // PV: B-frag assembled in-register via permlane 32+16 swap chains
      f32x4 oa = (f32x4){0, 0, 0, 0};
      #pragma unroll
      for (int ks = 0; ks < 2; ++ks) {
        if (ks * 2 > qt) continue;
        unsigned x = pa[2 * ks], y = pa[2 * ks + 1];
        asm("v_permlane32_swap_b32 %0, %1" : "+v"(x), "+v"(y));
        asm("v_permlane16_swap_b32 %0, %1" : "+v"(x), "+v"(y));
        unsigned u2 = pb[2 * ks], v2 = pb[2 * ks + 1];
        asm("v_permlane32_swap_b32 %0, %1" : "+v"(u2), "+v"(v2));
        asm("v_permlane16_swap_b32 %0, %1" : "+v"(u2), "+v"(v2));
        union { unsigned uw[4]; bf16x8 h; } pu;
        pu.uw[0] = x; pu.uw[1] = u2; pu.uw[2] = y; pu.uw[3] = v2;
        oa = __builtin_amdgcn_mfma_f32_16x16x32_bf16(vf[ks], pu.h, oa, 0, 0, 0);
      }
      // O^T layout: lane li owns row qt*16+li, cols hc+4lg..+3 -> one b64 store
      uint2 ov;
      ov.x = cvtpk(oa[0] * rinv, oa[1] * rinv);
      ov.y = cvtpk(oa[2] * rinv, oa[3] * rinv);
      *(uint2*)(Qb + swz128(qt * 16 + li, hc + lg * 4)) = ov;  // strip w: Q dead
    }
  }

  bf16x8 preO1[4];
  pf_b1<128>(wo1t, c0, li, lg, preO1);   // in flight across B2
  bar();  // B2: attention done; AO (=Qb) visible; Kb/Vt free

  // ---------------- O1, O2 + residual -------------------------------------
  bf16x8 af4[4];
  load_af128<4>(Qb, q0 + li, af4, lg);     // AO
  f32x4 a1[4];
  #pragma unroll
  for (int i = 0; i < 4; ++i) a1[i] = (f32x4){0, 0, 0, 0};
  gemm4_pre<128>(af4, wo1t, c0, a1, li, lg, preO1);
  epi4(a1, bo1, H1, true, li, lg, q0, c0);

  bf16x8 preO2[4];
  pf_b1<128>(wo2t, c0, li, lg, preO2);
  bar();  // B3: H1 visible

  // residual x loads issued here: hidden under the O2 GEMM
  float xr[4][4];
  #pragma unroll
  for (int ct = 0; ct < 4; ++ct)
    #pragma unroll
    for (int r = 0; r < 4; ++r)
      xr[ct][r] = xbase[(q0 + lg * 4 + r) * rs + c0 + ct * 16 + li];

  load_af128<4>(H1, q0 + li, af4, lg);
  f32x4 ya[4];
  #pragma unroll
  for (int i = 0; i < 4; ++i) ya[i] = (f32x4){0, 0, 0, 0};
  gemm4_pre<128>(af4, wo2t, c0, ya, li, lg, preO2);

  float x2r[4][4];
  #pragma unroll
  for (int ct = 0; ct < 4; ++ct) {
    float bvv = bo2[c0 + ct * 16 + li];
    #pragma unroll
    for (int r = 0; r < 4; ++r)
      x2r[ct][r] = ya[ct][r] + bvv + xr[ct][r];
  }

  // ---------------- LN2 (cross-pair partials via LDS) ---------------------
  float s1v[4], s2v[4];
  #pragma unroll
  for (int r = 0; r < 4; ++r) {
    float s1 = 0.0f, s2 = 0.0f;
    #pragma unroll
    for (int ct = 0; ct < 4; ++ct) {
      float v = x2r[ct][r];
      s1 += v; s2 += v * v;
    }
    s1 = red16(s1);
    s2 = red16(s2);
    s1v[r] = s1; s2v[r] = s2;
    if (li == 0) {
      int row = q0 + lg * 4 + r;
      lnpf[row * 4 + wc * 2]     = s1;
      lnpf[row * 4 + wc * 2 + 1] = s2;
    }
  }
  bf16x8 preF1[4];
  pf_b1<128>(wf1t, c0, li, lg, preF1);
  bar();  // B4: partials visible; Vt region -> Xn2

  float g2v[4], b2v[4];
  #pragma unroll
  for (int ct = 0; ct < 4; ++ct) {
    g2v[ct] = g2[c0 + ct * 16 + li];
    b2v[ct] = b2[c0 + ct * 16 + li];
  }
  #pragma unroll
  for (int r = 0; r < 4; ++r) {
    int row = q0 + lg * 4 + r;
    float s1 = s1v[r] + lnpf[row * 4 + (1 - wc) * 2];
    float s2 = s2v[r] + lnpf[row * 4 + (1 - wc) * 2 + 1];
    float mean = s1 * (1.0f / 128.0f);
    float var = fmaxf((s2 - s1 * mean) * (1.0f / 127.0f), 0.0f);
    float inv = 1.0f / (sqrtf(var) + 1e-6f);
    #pragma unroll
    for (int ct = 0; ct < 4; ++ct)
      Xn2[swz128(row, c0 + ct * 16 + li)] =
          f2bf(g2v[ct] * (x2r[ct][r] - mean) * inv + b2v[ct]);
  }
  bar();  // B5: Xn2 visible; Qb/AO region -> Hf

  // ---------------- FFN + final residual ----------------------------------
  load_af128<4>(Xn2, q0 + li, af4, lg);
  f32x4 f1a[4];
  #pragma unroll
  for (int i = 0; i < 4; ++i) f1a[i] = (f32x4){0, 0, 0, 0};
  gemm4_pre<128>(af4, wf1t, c0, f1a, li, lg, preF1);
  epi4(f1a, bf1, Hf, true, li, lg, q0, c0);

  bf16x8 preF2[4];
  pf_b1<128>(wf2t, c0, li, lg, preF2);
  bar();  // B6: Hf visible

  load_af128<4>(Hf, q0 + li, af4, lg);
  f32x4 f2a[4];
  #pragma unroll
  for (int i = 0; i < 4; ++i) f2a[i] = (f32x4){0, 0, 0, 0};
  gemm4_pre<128>(af4, wf2t, c0, f2a, li, lg, preF2);

  float* obase = out + (b * TT * NN + n) * DD;
  #pragma unroll
  for (int ct = 0; ct < 4; ++ct) {
    float bvv = bf2[c0 + ct * 16 + li];
    #pragma unroll
    for (int r = 0; r < 4; ++r)
      obase[(q0 + lg * 4 + r) * rs + c0 + ct * 16 + li] =
          x2r[ct][r] + fmaxf(f2a[ct][r] + bvv, 0.0f);
  }
  #undef SWZ256
}

extern "C" void kernel_launch(void* const* d_in, const int* in_sizes, int n_in,
                              void* d_out, int out_size, void* d_ws, size_t ws_size,
                              hipStream_t stream) {
  const float* x   = (const float*)d_in[0];
  const float* ste = (const float*)d_in[1];
  const float* g1 = (const float*)d_in[3];
  const float* b1 = (const float*)d_in[4];
  const float* g2 = (const float*)d_in[5];
  const float* b2 = (const float*)d_in[6];
  const float* Wq = (const float*)d_in[7];   const float* bq  = (const float*)d_in[8];
  const float* Wk = (const float*)d_in[9];   const float* bk  = (const float*)d_in[10];
  const float* Wv = (const float*)d_in[11];  const float* bv  = (const float*)d_in[12];
  const float* Wo1 = (const float*)d_in[13]; const float* bo1 = (const float*)d_in[14];
  const float* Wo2 = (const float*)d_in[15]; const float* bo2 = (const float*)d_in[16];
  const float* Wf1 = (const float*)d_in[17]; const float* bf1 = (const float*)d_in[18];
  const float* Wf2 = (const float*)d_in[19]; const float* bf2 = (const float*)d_in[20];
  float* out = (float*)d_out;

  unsigned short* wsu = (unsigned short*)d_ws;
  unsigned short* wq_t  = wsu;             // [128][256]
  unsigned short* wk_t  = wsu + 32768;
  unsigned short* wv_t  = wsu + 65536;
  unsigned short* wo1_t = wsu + 98304;     // [128][128]
  unsigned short* wo2_t = wsu + 114688;
  unsigned short* wf1_t = wsu + 131072;
  unsigned short* wf2_t = wsu + 147456;

  hipLaunchKernelGGL(wprep, dim3(128), dim3(256), 0, stream, Wq, wq_t, 256, 128);
  hipLaunchKernelGGL(wprep, dim3(128), dim3(256), 0, stream, Wk, wk_t, 256, 128);
  hipLaunchKernelGGL(wprep, dim3(128), dim3(256), 0, stream, Wv, wv_t, 256, 128);
  hipLaunchKernelGGL(wprep, dim3(64), dim3(256), 0, stream, Wo1, wo1_t, 128, 128);
  hipLaunchKernelGGL(wprep, dim3(64), dim3(256), 0, stream, Wo2, wo2_t, 128, 128);
  hipLaunchKernelGGL(wprep, dim3(64), dim3(256), 0, stream, Wf1, wf1_t, 128, 128);
  hipLaunchKernelGGL(wprep, dim3(64), dim3(256), 0, stream, Wf2, wf2_t, 128, 128);

  hipLaunchKernelGGL(fused_layer, dim3(8 * NN), dim3(512), 0, stream,
                     x, ste, g1, b1, g2, b2,
                     wq_t, bq, wk_t, bk, wv_t, bv,
                     wo1_t, bo1, wo2_t, bo2,
                     wf1_t, bf1, wf2_t, bf2, out);
}

// Round 8
// 511.285 us; speedup vs baseline: 1.0138x; 1.0138x over previous
//
#include <hip/hip_runtime.h>

#define TT 64
#define NN 512
#define DD 128

typedef __attribute__((ext_vector_type(8))) short bf16x8;
typedef __attribute__((ext_vector_type(4))) float f32x4;

__device__ __forceinline__ unsigned short f2bf(float f) {
  unsigned int u = __float_as_uint(f);
  u += 0x7fffu + ((u >> 16) & 1u);          // RNE
  return (unsigned short)(u >> 16);
}

__device__ __forceinline__ unsigned cvtpk(float lo, float hi) {
  unsigned r;
  asm("v_cvt_pk_bf16_f32 %0, %1, %2" : "=v"(r) : "v"(lo), "v"(hi));
  return r;
}

// XOR-swizzled LDS index helpers (units: unsigned short elements).
__device__ __forceinline__ int swz128(int row, int col) {
  return row * 128 + (((col >> 3) ^ (row & 15)) << 3) + (col & 7);
}
__device__ __forceinline__ int swz64(int row, int col) {
  return row * 64 + (((col >> 3) ^ (row & 7)) << 3) + (col & 7);
}

// Barrier with LDS-only drain: global loads stay in flight across it.
__device__ __forceinline__ void bar() {
  asm volatile("s_waitcnt lgkmcnt(0)" ::: "memory");
  __builtin_amdgcn_s_barrier();
  asm volatile("" ::: "memory");
}

// 16-lane (DPP-row) sum via row_ror butterflies — VALU pipe, no LDS traffic.
__device__ __forceinline__ float red16(float s) {
  int t;
  t = __builtin_amdgcn_update_dpp(0, __float_as_int(s), 0x121, 0xf, 0xf, false);
  s += __int_as_float(t);
  t = __builtin_amdgcn_update_dpp(0, __float_as_int(s), 0x122, 0xf, 0xf, false);
  s += __int_as_float(t);
  t = __builtin_amdgcn_update_dpp(0, __float_as_int(s), 0x124, 0xf, 0xf, false);
  s += __int_as_float(t);
  t = __builtin_amdgcn_update_dpp(0, __float_as_int(s), 0x128, 0xf, 0xf, false);
  s += __int_as_float(t);
  return s;
}

// Prefetch kk=0 B-fragments (issued a stage early; survive lgkm barriers).
template<int KDIM>
__device__ __forceinline__ void pf_b1(const unsigned short* __restrict__ Bg, int c0,
                                      int li, int lg, bf16x8 pre[4]) {
  #pragma unroll
  for (int ct = 0; ct < 4; ++ct)
    pre[ct] = *(const bf16x8*)(Bg + (c0 + ct * 16 + li) * KDIM + lg * 8);
}

template<int KDIM>
__device__ __forceinline__ void gemm4_pre(const bf16x8* af, const unsigned short* __restrict__ Bg,
                                          int c0, f32x4 acc[4], int li, int lg,
                                          const bf16x8 pre[4]) {
  #pragma unroll
  for (int kk = 0; kk < KDIM / 32; ++kk) {
    #pragma unroll
    for (int ct = 0; ct < 4; ++ct) {
      bf16x8 bfr;
      if (kk == 0) bfr = pre[ct];
      else bfr = *(const bf16x8*)(Bg + (c0 + ct * 16 + li) * KDIM + kk * 32 + lg * 8);
      acc[ct] = __builtin_amdgcn_mfma_f32_16x16x32_bf16(af[kk], bfr, acc[ct], 0, 0, 0);
    }
  }
}

template<int NFR>
__device__ __forceinline__ void load_af128(const unsigned short* As, int row, bf16x8* af, int lg) {
  #pragma unroll
  for (int kk = 0; kk < NFR; ++kk)
    af[kk] = *(const bf16x8*)(As + swz128(row, kk * 32 + lg * 8));
}

__device__ __forceinline__ void epi4(const f32x4 acc[4], const float* __restrict__ bias,
                                     unsigned short* dst, bool relu,
                                     int li, int lg, int q0, int c0) {
  #pragma unroll
  for (int ct = 0; ct < 4; ++ct) {
    float bv = bias[c0 + ct * 16 + li];
    #pragma unroll
    for (int r = 0; r < 4; ++r) {
      float v = acc[ct][r] + bv;
      if (relu) v = fmaxf(v, 0.0f);
      dst[swz128(q0 + lg * 4 + r, c0 + ct * 16 + li)] = f2bf(v);
    }
  }
}

// transpose fp32 [K][N] -> bf16 [N][K]
__global__ void wprep(const float* __restrict__ src, unsigned short* __restrict__ dst,
                      int K, int Nn) {
  int idx = blockIdx.x * 256 + threadIdx.x;
  if (idx >= K * Nn) return;
  int n = idx / K, k = idx - n * K;
  dst[idx] = f2bf(src[k * Nn + n]);
}

#define KSCL 0.36067376022224085f   // 0.25 * log2(e), folded into K epilogue

__global__ __launch_bounds__(512, 6)
void fused_layer(const float* __restrict__ x_in, const float* __restrict__ ste,
                 const float* __restrict__ g1, const float* __restrict__ b1,
                 const float* __restrict__ g2, const float* __restrict__ b2,
                 const unsigned short* __restrict__ wqt, const float* __restrict__ bq,
                 const unsigned short* __restrict__ wkt, const float* __restrict__ bk,
                 const unsigned short* __restrict__ wvt, const float* __restrict__ bv,
                 const unsigned short* __restrict__ wo1t, const float* __restrict__ bo1,
                 const unsigned short* __restrict__ wo2t, const float* __restrict__ bo2,
                 const unsigned short* __restrict__ wf1t, const float* __restrict__ bf1,
                 const unsigned short* __restrict__ wf2t, const float* __restrict__ bf2,
                 float* __restrict__ out) {
  __shared__ __align__(16) unsigned short smem[25088];  // 49 KB

  const int tid = threadIdx.x;
  const int lane = tid & 63;
  const int w  = tid >> 6;         // wave 0..7
  const int wr = w >> 1;           // row group (rows 16wr..16wr+15)
  const int wc = w & 1;            // col half
  const int lg = lane >> 4;        // 0..3
  const int li = lane & 15;
  const int q0 = wr * 16;
  const int c0 = wc * 64;

  const int blk = blockIdx.x;
  const int b = blk >> 9;          // N=512
  const int n = blk & 511;
  const int rs = NN * DD;
  const float* xbase = x_in + (b * TT * NN + n) * DD;
  const float* sbase = ste + (b * TT * NN + n) * DD;

  // Region plan (lifetimes guarded by barriers):
  //  [0..16384)      X2s [64][256] bf16 (xnorm|STE), dead after B0e
  //  [0..8192)       post-B0e: Qb [64][128] (Q, then AO strips)   | post-B5: Hf
  //  [8192..16384)   post-B0e: Kb [64][128]                       | post-B2: H1
  //  [16384..24576)  Vt [128][64] (V^T; written pre-B0e, no overlay) | post-B4: Xn2
  //  [24576..25088)  lnpf (LN2 partials, 1KB)
  unsigned short* X2s = smem;
  unsigned short* Qb  = smem;
  unsigned short* Kb  = smem + 8192;
  unsigned short* Vt  = smem + 16384;
  unsigned short* H1  = smem + 8192;
  unsigned short* Xn2 = smem + 16384;
  unsigned short* Hf  = smem;
  float* lnpf = (float*)(smem + 24576);

  #define SWZ256(row, col) ((row) * 256 + ((((col) >> 3) ^ ((row) & 15)) << 3) + ((col) & 7))

  // ---------------- LN1 + STE -> X2 (16 lanes per row; rows w*8..w*8+7) ----
  {
    float4 gA = *(const float4*)(g1 + li * 8);
    float4 gB = *(const float4*)(g1 + li * 8 + 4);
    float4 bA = *(const float4*)(b1 + li * 8);
    float4 bB = *(const float4*)(b1 + li * 8 + 4);
    #pragma unroll
    for (int pass = 0; pass < 2; ++pass) {
      int t = w * 8 + pass * 4 + lg;
      float4 xA = *(const float4*)(xbase + t * rs + li * 8);
      float4 xB = *(const float4*)(xbase + t * rs + li * 8 + 4);
      float s1 = xA.x + xA.y + xA.z + xA.w + xB.x + xB.y + xB.z + xB.w;
      float s2 = xA.x * xA.x + xA.y * xA.y + xA.z * xA.z + xA.w * xA.w +
                 xB.x * xB.x + xB.y * xB.y + xB.z * xB.z + xB.w * xB.w;
      s1 = red16(s1);
      s2 = red16(s2);
      float mean = s1 * (1.0f / 128.0f);
      float var = fmaxf((s2 - s1 * mean) * (1.0f / 127.0f), 0.0f);  // ddof=1
      float inv = 1.0f / (sqrtf(var) + 1e-6f);
      bf16x8 o;
      o[0] = (short)f2bf(gA.x * (xA.x - mean) * inv + bA.x);
      o[1] = (short)f2bf(gA.y * (xA.y - mean) * inv + bA.y);
      o[2] = (short)f2bf(gA.z * (xA.z - mean) * inv + bA.z);
      o[3] = (short)f2bf(gA.w * (xA.w - mean) * inv + bA.w);
      o[4] = (short)f2bf(gB.x * (xB.x - mean) * inv + bB.x);
      o[5] = (short)f2bf(gB.y * (xB.y - mean) * inv + bB.y);
      o[6] = (short)f2bf(gB.z * (xB.z - mean) * inv + bB.z);
      o[7] = (short)f2bf(gB.w * (xB.w - mean) * inv + bB.w);
      *(bf16x8*)(X2s + SWZ256(t, li * 8)) = o;
      float4 sA = *(const float4*)(sbase + t * rs + li * 8);
      float4 sB = *(const float4*)(sbase + t * rs + li * 8 + 4);
      bf16x8 so;
      so[0] = (short)f2bf(sA.x); so[1] = (short)f2bf(sA.y);
      so[2] = (short)f2bf(sA.z); so[3] = (short)f2bf(sA.w);
      so[4] = (short)f2bf(sB.x); so[5] = (short)f2bf(sB.y);
      so[6] = (short)f2bf(sB.z); so[7] = (short)f2bf(sB.w);
      *(bf16x8*)(X2s + SWZ256(t, 128 + li * 8)) = so;
    }
  }

  bar();  // B0: X2 visible

  // ---------------- V-pass (wave w -> V cols 16w..16w+15), retire early ----
  {
    const unsigned short* vB = wvt + (w * 16) * 256;
    f32x4 va[4];
    #pragma unroll
    for (int rg = 0; rg < 4; ++rg) va[rg] = (f32x4){0, 0, 0, 0};
    #pragma unroll
    for (int kk = 0; kk < 8; ++kk) {
      bf16x8 bc = *(const bf16x8*)(vB + li * 256 + kk * 32 + lg * 8);
      #pragma unroll
      for (int rg = 0; rg < 4; ++rg) {
        bf16x8 af = *(const bf16x8*)(X2s + SWZ256(rg * 16 + li, kk * 32 + lg * 8));
        va[rg] = __builtin_amdgcn_mfma_f32_16x16x32_bf16(af, bc, va[rg], 0, 0, 0);
      }
    }
    // Vt is NOT an overlay region -> epilogue immediately, accs freed
    float bvv = bv[w * 16 + li];
    int d = w * 16 + li;
    #pragma unroll
    for (int rg = 0; rg < 4; ++rg) {
      float v0 = fmaxf(va[rg][0] + bvv, 0.0f);
      float v1 = fmaxf(va[rg][1] + bvv, 0.0f);
      float v2 = fmaxf(va[rg][2] + bvv, 0.0f);
      float v3 = fmaxf(va[rg][3] + bvv, 0.0f);
      uint2 pv; pv.x = cvtpk(v0, v1); pv.y = cvtpk(v2, v3);
      *(uint2*)(Vt + swz64(d, rg * 16 + lg * 4)) = pv;   // 8B aligned
    }
  }

  // ---------------- K-pass (wave w -> K cols 16w..16w+15) ------------------
  f32x4 ka[4];
  #pragma unroll
  for (int rg = 0; rg < 4; ++rg) ka[rg] = (f32x4){0, 0, 0, 0};
  {
    const unsigned short* kB = wkt + (w * 16) * 256;
    #pragma unroll
    for (int kk = 0; kk < 8; ++kk) {
      bf16x8 bc = *(const bf16x8*)(kB + li * 256 + kk * 32 + lg * 8);
      #pragma unroll
      for (int rg = 0; rg < 4; ++rg) {
        bf16x8 af = *(const bf16x8*)(X2s + SWZ256(rg * 16 + li, kk * 32 + lg * 8));
        ka[rg] = __builtin_amdgcn_mfma_f32_16x16x32_bf16(af, bc, ka[rg], 0, 0, 0);
      }
    }
  }

  // ---------------- Q-pass (own 16 rows x 64-col half) ---------------------
  f32x4 qacc[4];
  #pragma unroll
  for (int i = 0; i < 4; ++i) qacc[i] = (f32x4){0, 0, 0, 0};
  #pragma unroll
  for (int kk = 0; kk < 8; ++kk) {
    bf16x8 af = *(const bf16x8*)(X2s + SWZ256(q0 + li, kk * 32 + lg * 8));
    #pragma unroll
    for (int ct = 0; ct < 4; ++ct)
      qacc[ct] = __builtin_amdgcn_mfma_f32_16x16x32_bf16(
          af, *(const bf16x8*)(wqt + (c0 + ct * 16 + li) * 256 + kk * 32 + lg * 8),
          qacc[ct], 0, 0, 0);
  }

  bar();  // B0e: ALL X2 reads done; Vt writes drained -> Kb/Qb overlays live

  // K epilogue (scaled by 0.25*log2e) and Q epilogue into overlay regions
  {
    float bkv = bk[w * 16 + li];
    #pragma unroll
    for (int rg = 0; rg < 4; ++rg)
      #pragma unroll
      for (int r = 0; r < 4; ++r)
        Kb[swz128(rg * 16 + lg * 4 + r, w * 16 + li)] =
            f2bf(fmaxf(ka[rg][r] + bkv, 0.0f) * KSCL);
  }
  epi4(qacc, bq, Qb, true, li, lg, q0, c0);

  bar();  // B1: Kb/Vt/Qb visible everywhere

  // ---------------- causal attention, head-major (wave w = head w) --------
  {
    const int hc = w * 16;
    const bf16x8 zf = (bf16x8){0, 0, 0, 0, 0, 0, 0, 0};
    bf16x8 kf[4], vf[2];
    #pragma unroll
    for (int pt = 0; pt < 4; ++pt)
      kf[pt] = (lg < 2) ? *(const bf16x8*)(Kb + swz128(pt * 16 + li, hc + lg * 8)) : zf;
    #pragma unroll
    for (int ks = 0; ks < 2; ++ks)
      vf[ks] = *(const bf16x8*)(Vt + swz64(hc + li, ks * 32 + lg * 8));

    #pragma unroll
    for (int qt = 0; qt < 4; ++qt) {
      bf16x8 qf = (lg < 2) ? *(const bf16x8*)(Qb + swz128(qt * 16 + li, hc + lg * 8)) : zf;
      f32x4 st[4];
      #pragma unroll
      for (int pt = 0; pt < 4; ++pt)
        if (pt <= qt)   // compile-time after unroll: causal tile skip
          st[pt] = __builtin_amdgcn_mfma_f32_16x16x32_bf16(kf[pt], qf, (f32x4){0, 0, 0, 0}, 0, 0, 0);

      // exp (scale pre-folded into K); pack P^T pairs; row-sum (q = qt*16+li)
      float ssum = 0.0f;
      unsigned pa[4], pb[4];
      #pragma unroll
      for (int pt = 0; pt < 4; ++pt) {
        if (pt > qt) { pa[pt] = 0; pb[pt] = 0; continue; }
        float e0 = exp2f(st[pt][0]);
        float e1 = exp2f(st[pt][1]);
        float e2 = exp2f(st[pt][2]);
        float e3 = exp2f(st[pt][3]);
        if (pt == qt) {  // diagonal tile: mask p_local > q_local
          e0 = (4 * lg + 0 > li) ? 0.0f : e0;
          e1 = (4 * lg + 1 > li) ? 0.0f : e1;
          e2 = (4 * lg + 2 > li) ? 0.0f : e2;
          e3 = (4 * lg + 3 > li) ? 0.0f : e3;
        }
        ssum += e0 + e1 + e2 + e3;
        pa[pt] = cvtpk(e0, e1);
        pb[pt] = cvtpk(e2, e3);
      }
      ssum += __shfl_xor(ssum, 16, 64);
      ssum += __shfl_xor(ssum, 32, 64);
      float rinv = 1.0f / ssum;

      // PV: B-frag assembled in-register via permlane 32+16 swap chains
      f32x4 oa = (f32x4){0, 0, 0, 0};
      #pragma unroll
      for (int ks = 0; ks < 2; ++ks) {
        if (ks * 2 > qt) continue;
        unsigned x = pa[2 * ks], y = pa[2 * ks + 1];
        asm("v_permlane32_swap_b32 %0, %1" : "+v"(x), "+v"(y));
        asm("v_permlane16_swap_b32 %0, %1" : "+v"(x), "+v"(y));
        unsigned u2 = pb[2 * ks], v2 = pb[2 * ks + 1];
        asm("v_permlane32_swap_b32 %0, %1" : "+v"(u2), "+v"(v2));
        asm("v_permlane16_swap_b32 %0, %1" : "+v"(u2), "+v"(v2));
        union { unsigned uw[4]; bf16x8 h; } pu;
        pu.uw[0] = x; pu.uw[1] = u2; pu.uw[2] = y; pu.uw[3] = v2;
        oa = __builtin_amdgcn_mfma_f32_16x16x32_bf16(vf[ks], pu.h, oa, 0, 0, 0);
      }
      // O^T layout: lane li owns row qt*16+li, cols hc+4lg..+3 -> one b64 store
      uint2 ov;
      ov.x = cvtpk(oa[0] * rinv, oa[1] * rinv);
      ov.y = cvtpk(oa[2] * rinv, oa[3] * rinv);
      *(uint2*)(Qb + swz128(qt * 16 + li, hc + lg * 4)) = ov;  // strip w: Q dead
    }
  }

  bf16x8 preO1[4];
  pf_b1<128>(wo1t, c0, li, lg, preO1);   // in flight across B2
  bar();  // B2: attention done; AO (=Qb) visible; Kb/Vt free

  // ---------------- O1, O2 + residual -------------------------------------
  bf16x8 af4[4];
  load_af128<4>(Qb, q0 + li, af4, lg);     // AO
  f32x4 a1[4];
  #pragma unroll
  for (int i = 0; i < 4; ++i) a1[i] = (f32x4){0, 0, 0, 0};
  gemm4_pre<128>(af4, wo1t, c0, a1, li, lg, preO1);
  epi4(a1, bo1, H1, true, li, lg, q0, c0);

  bf16x8 preO2[4];
  pf_b1<128>(wo2t, c0, li, lg, preO2);
  bar();  // B3: H1 visible

  // residual x loads issued here: hidden under the O2 GEMM
  float xr[4][4];
  #pragma unroll
  for (int ct = 0; ct < 4; ++ct)
    #pragma unroll
    for (int r = 0; r < 4; ++r)
      xr[ct][r] = xbase[(q0 + lg * 4 + r) * rs + c0 + ct * 16 + li];

  load_af128<4>(H1, q0 + li, af4, lg);
  f32x4 ya[4];
  #pragma unroll
  for (int i = 0; i < 4; ++i) ya[i] = (f32x4){0, 0, 0, 0};
  gemm4_pre<128>(af4, wo2t, c0, ya, li, lg, preO2);

  float x2r[4][4];
  #pragma unroll
  for (int ct = 0; ct < 4; ++ct) {
    float bvv = bo2[c0 + ct * 16 + li];
    #pragma unroll
    for (int r = 0; r < 4; ++r)
      x2r[ct][r] = ya[ct][r] + bvv + xr[ct][r];
  }

  // ---------------- LN2 (cross-pair partials via LDS) ---------------------
  float s1v[4], s2v[4];
  #pragma unroll
  for (int r = 0; r < 4; ++r) {
    float s1 = 0.0f, s2 = 0.0f;
    #pragma unroll
    for (int ct = 0; ct < 4; ++ct) {
      float v = x2r[ct][r];
      s1 += v; s2 += v * v;
    }
    s1 = red16(s1);
    s2 = red16(s2);
    s1v[r] = s1; s2v[r] = s2;
    if (li == 0) {
      int row = q0 + lg * 4 + r;
      lnpf[row * 4 + wc * 2]     = s1;
      lnpf[row * 4 + wc * 2 + 1] = s2;
    }
  }
  bf16x8 preF1[4];
  pf_b1<128>(wf1t, c0, li, lg, preF1);
  bar();  // B4: partials visible; Vt region -> Xn2

  float g2v[4], b2v[4];
  #pragma unroll
  for (int ct = 0; ct < 4; ++ct) {
    g2v[ct] = g2[c0 + ct * 16 + li];
    b2v[ct] = b2[c0 + ct * 16 + li];
  }
  #pragma unroll
  for (int r = 0; r < 4; ++r) {
    int row = q0 + lg * 4 + r;
    float s1 = s1v[r] + lnpf[row * 4 + (1 - wc) * 2];
    float s2 = s2v[r] + lnpf[row * 4 + (1 - wc) * 2 + 1];
    float mean = s1 * (1.0f / 128.0f);
    float var = fmaxf((s2 - s1 * mean) * (1.0f / 127.0f), 0.0f);
    float inv = 1.0f / (sqrtf(var) + 1e-6f);
    #pragma unroll
    for (int ct = 0; ct < 4; ++ct)
      Xn2[swz128(row, c0 + ct * 16 + li)] =
          f2bf(g2v[ct] * (x2r[ct][r] - mean) * inv + b2v[ct]);
  }
  bar();  // B5: Xn2 visible; Qb/AO region -> Hf

  // ---------------- FFN + final residual ----------------------------------
  load_af128<4>(Xn2, q0 + li, af4, lg);
  f32x4 f1a[4];
  #pragma unroll
  for (int i = 0; i < 4; ++i) f1a[i] = (f32x4){0, 0, 0, 0};
  gemm4_pre<128>(af4, wf1t, c0, f1a, li, lg, preF1);
  epi4(f1a, bf1, Hf, true, li, lg, q0, c0);

  bf16x8 preF2[4];
  pf_b1<128>(wf2t, c0, li, lg, preF2);
  bar();  // B6: Hf visible

  load_af128<4>(Hf, q0 + li, af4, lg);
  f32x4 f2a[4];
  #pragma unroll
  for (int i = 0; i < 4; ++i) f2a[i] = (f32x4){0, 0, 0, 0};
  gemm4_pre<128>(af4, wf2t, c0, f2a, li, lg, preF2);

  float* obase = out + (b * TT * NN + n) * DD;
  #pragma unroll
  for (int ct = 0; ct < 4; ++ct) {
    float bvv = bf2[c0 + ct * 16 + li];
    #pragma unroll
    for (int r = 0; r < 4; ++r)
      obase[(q0 + lg * 4 + r) * rs + c0 + ct * 16 + li] =
          x2r[ct][r] + fmaxf(f2a[ct][r] + bvv, 0.0f);
  }
  #undef SWZ256
}

extern "C" void kernel_launch(void* const* d_in, const int* in_sizes, int n_in,
                              void* d_out, int out_size, void* d_ws, size_t ws_size,
                              hipStream_t stream) {
  const float* x   = (const float*)d_in[0];
  const float* ste = (const float*)d_in[1];
  const float* g1 = (const float*)d_in[3];
  const float* b1 = (const float*)d_in[4];
  const float* g2 = (const float*)d_in[5];
  const float* b2 = (const float*)d_in[6];
  const float* Wq = (const float*)d_in[7];   const float* bq  = (const float*)d_in[8];
  const float* Wk = (const float*)d_in[9];   const float* bk  = (const float*)d_in[10];
  const float* Wv = (const float*)d_in[11];  const float* bv  = (const float*)d_in[12];
  const float* Wo1 = (const float*)d_in[13]; const float* bo1 = (const float*)d_in[14];
  const float* Wo2 = (const float*)d_in[15]; const float* bo2 = (const float*)d_in[16];
  const float* Wf1 = (const float*)d_in[17]; const float* bf1 = (const float*)d_in[18];
  const float* Wf2 = (const float*)d_in[19]; const float* bf2 = (const float*)d_in[20];
  float* out = (float*)d_out;

  unsigned short* wsu = (unsigned short*)d_ws;
  unsigned short* wq_t  = wsu;             // [128][256]
  unsigned short* wk_t  = wsu + 32768;
  unsigned short* wv_t  = wsu + 65536;
  unsigned short* wo1_t = wsu + 98304;     // [128][128]
  unsigned short* wo2_t = wsu + 114688;
  unsigned short* wf1_t = wsu + 131072;
  unsigned short* wf2_t = wsu + 147456;

  hipLaunchKernelGGL(wprep, dim3(128), dim3(256), 0, stream, Wq, wq_t, 256, 128);
  hipLaunchKernelGGL(wprep, dim3(128), dim3(256), 0, stream, Wk, wk_t, 256, 128);
  hipLaunchKernelGGL(wprep, dim3(128), dim3(256), 0, stream, Wv, wv_t, 256, 128);
  hipLaunchKernelGGL(wprep, dim3(64), dim3(256), 0, stream, Wo1, wo1_t, 128, 128);
  hipLaunchKernelGGL(wprep, dim3(64), dim3(256), 0, stream, Wo2, wo2_t, 128, 128);
  hipLaunchKernelGGL(wprep, dim3(64), dim3(256), 0, stream, Wf1, wf1_t, 128, 128);
  hipLaunchKernelGGL(wprep, dim3(64), dim3(256), 0, stream, Wf2, wf2_t, 128, 128);

  hipLaunchKernelGGL(fused_layer, dim3(8 * NN), dim3(512), 0, stream,
                     x, ste, g1, b1, g2, b2,
                     wq_t, bq, wk_t, bk, wv_t, bv,
                     wo1_t, bo1, wo2_t, bo2,
                     wf1_t, bf1, wf2_t, bf2, out);
}

// Round 9
// 477.742 us; speedup vs baseline: 1.0850x; 1.0702x over previous
//
#include <hip/hip_runtime.h>

#define TT 64
#define NN 512
#define DD 128

typedef __attribute__((ext_vector_type(8))) short bf16x8;
typedef __attribute__((ext_vector_type(4))) float f32x4;

__device__ __forceinline__ unsigned short f2bf(float f) {
  unsigned int u = __float_as_uint(f);
  u += 0x7fffu + ((u >> 16) & 1u);          // RNE
  return (unsigned short)(u >> 16);
}

__device__ __forceinline__ unsigned cvtpk(float lo, float hi) {
  unsigned r;
  asm("v_cvt_pk_bf16_f32 %0, %1, %2" : "=v"(r) : "v"(lo), "v"(hi));
  return r;
}

// XOR-swizzled LDS index helpers (units: unsigned short elements).
__device__ __forceinline__ int swz128(int row, int col) {
  return row * 128 + (((col >> 3) ^ (row & 15)) << 3) + (col & 7);
}
__device__ __forceinline__ int swz64(int row, int col) {
  return row * 64 + (((col >> 3) ^ (row & 7)) << 3) + (col & 7);
}

// Barrier with LDS-only drain: global loads stay in flight across it.
__device__ __forceinline__ void bar() {
  asm volatile("s_waitcnt lgkmcnt(0)" ::: "memory");
  __builtin_amdgcn_s_barrier();
  asm volatile("" ::: "memory");
}

// 16-lane (DPP-row) sum via row_ror butterflies — VALU pipe, no LDS traffic.
__device__ __forceinline__ float red16(float s) {
  int t;
  t = __builtin_amdgcn_update_dpp(0, __float_as_int(s), 0x121, 0xf, 0xf, false);
  s += __int_as_float(t);
  t = __builtin_amdgcn_update_dpp(0, __float_as_int(s), 0x122, 0xf, 0xf, false);
  s += __int_as_float(t);
  t = __builtin_amdgcn_update_dpp(0, __float_as_int(s), 0x124, 0xf, 0xf, false);
  s += __int_as_float(t);
  t = __builtin_amdgcn_update_dpp(0, __float_as_int(s), 0x128, 0xf, 0xf, false);
  s += __int_as_float(t);
  return s;
}

// Prefetch kk=0 B-fragments (issued a stage early; survive lgkm barriers).
template<int KDIM>
__device__ __forceinline__ void pf_b1(const unsigned short* __restrict__ Bg, int c0,
                                      int li, int lg, bf16x8 pre[4]) {
  #pragma unroll
  for (int ct = 0; ct < 4; ++ct)
    pre[ct] = *(const bf16x8*)(Bg + (c0 + ct * 16 + li) * KDIM + lg * 8);
}

template<int KDIM>
__device__ __forceinline__ void gemm4_pre(const bf16x8* af, const unsigned short* __restrict__ Bg,
                                          int c0, f32x4 acc[4], int li, int lg,
                                          const bf16x8 pre[4]) {
  #pragma unroll
  for (int kk = 0; kk < KDIM / 32; ++kk) {
    #pragma unroll
    for (int ct = 0; ct < 4; ++ct) {
      bf16x8 bfr;
      if (kk == 0) bfr = pre[ct];
      else bfr = *(const bf16x8*)(Bg + (c0 + ct * 16 + li) * KDIM + kk * 32 + lg * 8);
      acc[ct] = __builtin_amdgcn_mfma_f32_16x16x32_bf16(af[kk], bfr, acc[ct], 0, 0, 0);
    }
  }
}

template<int NFR>
__device__ __forceinline__ void load_af128(const unsigned short* As, int row, bf16x8* af, int lg) {
  #pragma unroll
  for (int kk = 0; kk < NFR; ++kk)
    af[kk] = *(const bf16x8*)(As + swz128(row, kk * 32 + lg * 8));
}

__device__ __forceinline__ void epi4(const f32x4 acc[4], const float* __restrict__ bias,
                                     unsigned short* dst, bool relu,
                                     int li, int lg, int q0, int c0) {
  #pragma unroll
  for (int ct = 0; ct < 4; ++ct) {
    float bv = bias[c0 + ct * 16 + li];
    #pragma unroll
    for (int r = 0; r < 4; ++r) {
      float v = acc[ct][r] + bv;
      if (relu) v = fmaxf(v, 0.0f);
      dst[swz128(q0 + lg * 4 + r, c0 + ct * 16 + li)] = f2bf(v);
    }
  }
}

// transpose fp32 [K][N] -> bf16 [N][K]
__global__ void wprep(const float* __restrict__ src, unsigned short* __restrict__ dst,
                      int K, int Nn) {
  int idx = blockIdx.x * 256 + threadIdx.x;
  if (idx >= K * Nn) return;
  int n = idx / K, k = idx - n * K;
  dst[idx] = f2bf(src[k * Nn + n]);
}

#define KSCL 0.36067376022224085f   // 0.25 * log2(e), folded into K epilogue

__global__ __launch_bounds__(512, 4)
void fused_layer(const float* __restrict__ x_in, const float* __restrict__ ste,
                 const float* __restrict__ g1, const float* __restrict__ b1,
                 const float* __restrict__ g2, const float* __restrict__ b2,
                 const unsigned short* __restrict__ wqt, const float* __restrict__ bq,
                 const unsigned short* __restrict__ wkt, const float* __restrict__ bk,
                 const unsigned short* __restrict__ wvt, const float* __restrict__ bv,
                 const unsigned short* __restrict__ wo1t, const float* __restrict__ bo1,
                 const unsigned short* __restrict__ wo2t, const float* __restrict__ bo2,
                 const unsigned short* __restrict__ wf1t, const float* __restrict__ bf1,
                 const unsigned short* __restrict__ wf2t, const float* __restrict__ bf2,
                 float* __restrict__ out) {
  __shared__ __align__(16) unsigned short smem[25088];  // 49 KB

  const int tid = threadIdx.x;
  const int lane = tid & 63;
  const int w  = tid >> 6;         // wave 0..7
  const int wr = w >> 1;           // row group (rows 16wr..16wr+15)
  const int wc = w & 1;            // col half
  const int lg = lane >> 4;        // 0..3
  const int li = lane & 15;
  const int q0 = wr * 16;
  const int c0 = wc * 64;

  const int blk = blockIdx.x;
  const int b = blk >> 9;          // N=512
  const int n = blk & 511;
  const int rs = NN * DD;
  const float* xbase = x_in + (b * TT * NN + n) * DD;
  const float* sbase = ste + (b * TT * NN + n) * DD;

  // Region plan (lifetimes guarded by barriers):
  //  [0..16384)      X2s [64][256] bf16 (xnorm|STE), dead after B0e
  //  [0..8192)       post-B0e: Qb [64][128] (Q, then AO strips)   | post-B5: Hf
  //  [8192..16384)   post-B0e: Kb [64][128]                       | post-B2: H1
  //  [16384..24576)  Vt [128][64] (V^T; written pre-B0e, no overlay) | post-B4: Xn2
  //  [24576..25088)  lnpf (LN2 partials, 1KB)
  unsigned short* X2s = smem;
  unsigned short* Qb  = smem;
  unsigned short* Kb  = smem + 8192;
  unsigned short* Vt  = smem + 16384;
  unsigned short* H1  = smem + 8192;
  unsigned short* Xn2 = smem + 16384;
  unsigned short* Hf  = smem;
  float* lnpf = (float*)(smem + 24576);

  #define SWZ256(row, col) ((row) * 256 + ((((col) >> 3) ^ ((row) & 15)) << 3) + ((col) & 7))

  // ---------------- LN1 + STE -> X2 (16 lanes per row; rows w*8..w*8+7) ----
  {
    float4 gA = *(const float4*)(g1 + li * 8);
    float4 gB = *(const float4*)(g1 + li * 8 + 4);
    float4 bA = *(const float4*)(b1 + li * 8);
    float4 bB = *(const float4*)(b1 + li * 8 + 4);
    #pragma unroll
    for (int pass = 0; pass < 2; ++pass) {
      int t = w * 8 + pass * 4 + lg;
      float4 xA = *(const float4*)(xbase + t * rs + li * 8);
      float4 xB = *(const float4*)(xbase + t * rs + li * 8 + 4);
      float s1 = xA.x + xA.y + xA.z + xA.w + xB.x + xB.y + xB.z + xB.w;
      float s2 = xA.x * xA.x + xA.y * xA.y + xA.z * xA.z + xA.w * xA.w +
                 xB.x * xB.x + xB.y * xB.y + xB.z * xB.z + xB.w * xB.w;
      s1 = red16(s1);
      s2 = red16(s2);
      float mean = s1 * (1.0f / 128.0f);
      float var = fmaxf((s2 - s1 * mean) * (1.0f / 127.0f), 0.0f);  // ddof=1
      float inv = 1.0f / (sqrtf(var) + 1e-6f);
      bf16x8 o;
      o[0] = (short)f2bf(gA.x * (xA.x - mean) * inv + bA.x);
      o[1] = (short)f2bf(gA.y * (xA.y - mean) * inv + bA.y);
      o[2] = (short)f2bf(gA.z * (xA.z - mean) * inv + bA.z);
      o[3] = (short)f2bf(gA.w * (xA.w - mean) * inv + bA.w);
      o[4] = (short)f2bf(gB.x * (xB.x - mean) * inv + bB.x);
      o[5] = (short)f2bf(gB.y * (xB.y - mean) * inv + bB.y);
      o[6] = (short)f2bf(gB.z * (xB.z - mean) * inv + bB.z);
      o[7] = (short)f2bf(gB.w * (xB.w - mean) * inv + bB.w);
      *(bf16x8*)(X2s + SWZ256(t, li * 8)) = o;
      float4 sA = *(const float4*)(sbase + t * rs + li * 8);
      float4 sB = *(const float4*)(sbase + t * rs + li * 8 + 4);
      bf16x8 so;
      so[0] = (short)f2bf(sA.x); so[1] = (short)f2bf(sA.y);
      so[2] = (short)f2bf(sA.z); so[3] = (short)f2bf(sA.w);
      so[4] = (short)f2bf(sB.x); so[5] = (short)f2bf(sB.y);
      so[6] = (short)f2bf(sB.z); so[7] = (short)f2bf(sB.w);
      *(bf16x8*)(X2s + SWZ256(t, 128 + li * 8)) = so;
    }
  }

  bar();  // B0: X2 visible

  // ---------------- V-pass (wave w -> V cols 16w..16w+15), retire early ----
  {
    const unsigned short* vB = wvt + (w * 16) * 256;
    f32x4 va[4];
    #pragma unroll
    for (int rg = 0; rg < 4; ++rg) va[rg] = (f32x4){0, 0, 0, 0};
    #pragma unroll
    for (int kk = 0; kk < 8; ++kk) {
      bf16x8 bc = *(const bf16x8*)(vB + li * 256 + kk * 32 + lg * 8);
      #pragma unroll
      for (int rg = 0; rg < 4; ++rg) {
        bf16x8 af = *(const bf16x8*)(X2s + SWZ256(rg * 16 + li, kk * 32 + lg * 8));
        va[rg] = __builtin_amdgcn_mfma_f32_16x16x32_bf16(af, bc, va[rg], 0, 0, 0);
      }
    }
    // Vt is NOT an overlay region -> epilogue immediately, accs freed
    float bvv = bv[w * 16 + li];
    int d = w * 16 + li;
    #pragma unroll
    for (int rg = 0; rg < 4; ++rg) {
      float v0 = fmaxf(va[rg][0] + bvv, 0.0f);
      float v1 = fmaxf(va[rg][1] + bvv, 0.0f);
      float v2 = fmaxf(va[rg][2] + bvv, 0.0f);
      float v3 = fmaxf(va[rg][3] + bvv, 0.0f);
      uint2 pv; pv.x = cvtpk(v0, v1); pv.y = cvtpk(v2, v3);
      *(uint2*)(Vt + swz64(d, rg * 16 + lg * 4)) = pv;   // 8B aligned
    }
  }

  // ---------------- K-pass (wave w -> K cols 16w..16w+15) ------------------
  f32x4 ka[4];
  #pragma unroll
  for (int rg = 0; rg < 4; ++rg) ka[rg] = (f32x4){0, 0, 0, 0};
  {
    const unsigned short* kB = wkt + (w * 16) * 256;
    #pragma unroll
    for (int kk = 0; kk < 8; ++kk) {
      bf16x8 bc = *(const bf16x8*)(kB + li * 256 + kk * 32 + lg * 8);
      #pragma unroll
      for (int rg = 0; rg < 4; ++rg) {
        bf16x8 af = *(const bf16x8*)(X2s + SWZ256(rg * 16 + li, kk * 32 + lg * 8));
        ka[rg] = __builtin_amdgcn_mfma_f32_16x16x32_bf16(af, bc, ka[rg], 0, 0, 0);
      }
    }
  }

  // ---------------- Q-pass (own 16 rows x 64-col half) ---------------------
  f32x4 qacc[4];
  #pragma unroll
  for (int i = 0; i < 4; ++i) qacc[i] = (f32x4){0, 0, 0, 0};
  #pragma unroll
  for (int kk = 0; kk < 8; ++kk) {
    bf16x8 af = *(const bf16x8*)(X2s + SWZ256(q0 + li, kk * 32 + lg * 8));
    #pragma unroll
    for (int ct = 0; ct < 4; ++ct)
      qacc[ct] = __builtin_amdgcn_mfma_f32_16x16x32_bf16(
          af, *(const bf16x8*)(wqt + (c0 + ct * 16 + li) * 256 + kk * 32 + lg * 8),
          qacc[ct], 0, 0, 0);
  }

  bar();  // B0e: ALL X2 reads done; Vt writes drained -> Kb/Qb overlays live

  // K epilogue (scaled by 0.25*log2e) and Q epilogue into overlay regions
  {
    float bkv = bk[w * 16 + li];
    #pragma unroll
    for (int rg = 0; rg < 4; ++rg)
      #pragma unroll
      for (int r = 0; r < 4; ++r)
        Kb[swz128(rg * 16 + lg * 4 + r, w * 16 + li)] =
            f2bf(fmaxf(ka[rg][r] + bkv, 0.0f) * KSCL);
  }
  epi4(qacc, bq, Qb, true, li, lg, q0, c0);

  bar();  // B1: Kb/Vt/Qb visible everywhere

  // ---------------- causal attention, head-major (wave w = head w) --------
  {
    const int hc = w * 16;
    const bf16x8 zf = (bf16x8){0, 0, 0, 0, 0, 0, 0, 0};
    bf16x8 kf[4], vf[2];
    #pragma unroll
    for (int pt = 0; pt < 4; ++pt)
      kf[pt] = (lg < 2) ? *(const bf16x8*)(Kb + swz128(pt * 16 + li, hc + lg * 8)) : zf;
    #pragma unroll
    for (int ks = 0; ks < 2; ++ks)
      vf[ks] = *(const bf16x8*)(Vt + swz64(hc + li, ks * 32 + lg * 8));

    #pragma unroll
    for (int qt = 0; qt < 4; ++qt) {
      bf16x8 qf = (lg < 2) ? *(const bf16x8*)(Qb + swz128(qt * 16 + li, hc + lg * 8)) : zf;
      f32x4 st[4];
      #pragma unroll
      for (int pt = 0; pt < 4; ++pt)
        if (pt <= qt)   // compile-time after unroll: causal tile skip
          st[pt] = __builtin_amdgcn_mfma_f32_16x16x32_bf16(kf[pt], qf, (f32x4){0, 0, 0, 0}, 0, 0, 0);

      // exp (scale pre-folded into K); pack P^T pairs; row-sum (q = qt*16+li)
      float ssum = 0.0f;
      unsigned pa[4], pb[4];
      #pragma unroll
      for (int pt = 0; pt < 4; ++pt) {
        if (pt > qt) { pa[pt] = 0; pb[pt] = 0; continue; }
        float e0 = exp2f(st[pt][0]);
        float e1 = exp2f(st[pt][1]);
        float e2 = exp2f(st[pt][2]);
        float e3 = exp2f(st[pt][3]);
        if (pt == qt) {  // diagonal tile: mask p_local > q_local
          e0 = (4 * lg + 0 > li) ? 0.0f : e0;
          e1 = (4 * lg + 1 > li) ? 0.0f : e1;
          e2 = (4 * lg + 2 > li) ? 0.0f : e2;
          e3 = (4 * lg + 3 > li) ? 0.0f : e3;
        }
        ssum += e0 + e1 + e2 + e3;
        pa[pt] = cvtpk(e0, e1);
        pb[pt] = cvtpk(e2, e3);
      }
      ssum += __shfl_xor(ssum, 16, 64);
      ssum += __shfl_xor(ssum, 32, 64);
      float rinv = 1.0f / ssum;

      // PV: B-frag assembled in-register via permlane 32+16 swap chains
      f32x4 oa = (f32x4){0, 0, 0, 0};
      #pragma unroll
      for (int ks = 0; ks < 2; ++ks) {
        if (ks * 2 > qt) continue;
        unsigned x = pa[2 * ks], y = pa[2 * ks + 1];
        asm("v_permlane32_swap_b32 %0, %1" : "+v"(x), "+v"(y));
        asm("v_permlane16_swap_b32 %0, %1" : "+v"(x), "+v"(y));
        unsigned u2 = pb[2 * ks], v2 = pb[2 * ks + 1];
        asm("v_permlane32_swap_b32 %0, %1" : "+v"(u2), "+v"(v2));
        asm("v_permlane16_swap_b32 %0, %1" : "+v"(u2), "+v"(v2));
        union { unsigned uw[4]; bf16x8 h; } pu;
        pu.uw[0] = x; pu.uw[1] = u2; pu.uw[2] = y; pu.uw[3] = v2;
        oa = __builtin_amdgcn_mfma_f32_16x16x32_bf16(vf[ks], pu.h, oa, 0, 0, 0);
      }
      // O^T layout: lane li owns row qt*16+li, cols hc+4lg..+3 -> one b64 store
      uint2 ov;
      ov.x = cvtpk(oa[0] * rinv, oa[1] * rinv);
      ov.y = cvtpk(oa[2] * rinv, oa[3] * rinv);
      *(uint2*)(Qb + swz128(qt * 16 + li, hc + lg * 4)) = ov;  // strip w: Q dead
    }
  }

  bf16x8 preO1[4];
  pf_b1<128>(wo1t, c0, li, lg, preO1);   // in flight across B2
  bar();  // B2: attention done; AO (=Qb) visible; Kb/Vt free

  // ---------------- O1, O2 + residual -------------------------------------
  bf16x8 af4[4];
  load_af128<4>(Qb, q0 + li, af4, lg);     // AO
  f32x4 a1[4];
  #pragma unroll
  for (int i = 0; i < 4; ++i) a1[i] = (f32x4){0, 0, 0, 0};
  gemm4_pre<128>(af4, wo1t, c0, a1, li, lg, preO1);
  epi4(a1, bo1, H1, true, li, lg, q0, c0);

  bf16x8 preO2[4];
  pf_b1<128>(wo2t, c0, li, lg, preO2);
  bar();  // B3: H1 visible

  // residual x loads issued here: hidden under the O2 GEMM
  float xr[4][4];
  #pragma unroll
  for (int ct = 0; ct < 4; ++ct)
    #pragma unroll
    for (int r = 0; r < 4; ++r)
      xr[ct][r] = xbase[(q0 + lg * 4 + r) * rs + c0 + ct * 16 + li];

  load_af128<4>(H1, q0 + li, af4, lg);
  f32x4 ya[4];
  #pragma unroll
  for (int i = 0; i < 4; ++i) ya[i] = (f32x4){0, 0, 0, 0};
  gemm4_pre<128>(af4, wo2t, c0, ya, li, lg, preO2);

  float x2r[4][4];
  #pragma unroll
  for (int ct = 0; ct < 4; ++ct) {
    float bvv = bo2[c0 + ct * 16 + li];
    #pragma unroll
    for (int r = 0; r < 4; ++r)
      x2r[ct][r] = ya[ct][r] + bvv + xr[ct][r];
  }

  // ---------------- LN2 (cross-pair partials via LDS) ---------------------
  float s1v[4], s2v[4];
  #pragma unroll
  for (int r = 0; r < 4; ++r) {
    float s1 = 0.0f, s2 = 0.0f;
    #pragma unroll
    for (int ct = 0; ct < 4; ++ct) {
      float v = x2r[ct][r];
      s1 += v; s2 += v * v;
    }
    s1 = red16(s1);
    s2 = red16(s2);
    s1v[r] = s1; s2v[r] = s2;
    if (li == 0) {
      int row = q0 + lg * 4 + r;
      lnpf[row * 4 + wc * 2]     = s1;
      lnpf[row * 4 + wc * 2 + 1] = s2;
    }
  }
  bf16x8 preF1[4];
  pf_b1<128>(wf1t, c0, li, lg, preF1);
  bar();  // B4: partials visible; Vt region -> Xn2

  float g2v[4], b2v[4];
  #pragma unroll
  for (int ct = 0; ct < 4; ++ct) {
    g2v[ct] = g2[c0 + ct * 16 + li];
    b2v[ct] = b2[c0 + ct * 16 + li];
  }
  #pragma unroll
  for (int r = 0; r < 4; ++r) {
    int row = q0 + lg * 4 + r;
    float s1 = s1v[r] + lnpf[row * 4 + (1 - wc) * 2];
    float s2 = s2v[r] + lnpf[row * 4 + (1 - wc) * 2 + 1];
    float mean = s1 * (1.0f / 128.0f);
    float var = fmaxf((s2 - s1 * mean) * (1.0f / 127.0f), 0.0f);
    float inv = 1.0f / (sqrtf(var) + 1e-6f);
    #pragma unroll
    for (int ct = 0; ct < 4; ++ct)
      Xn2[swz128(row, c0 + ct * 16 + li)] =
          f2bf(g2v[ct] * (x2r[ct][r] - mean) * inv + b2v[ct]);
  }
  bar();  // B5: Xn2 visible; Qb/AO region -> Hf

  // ---------------- FFN + final residual ----------------------------------
  load_af128<4>(Xn2, q0 + li, af4, lg);
  f32x4 f1a[4];
  #pragma unroll
  for (int i = 0; i < 4; ++i) f1a[i] = (f32x4){0, 0, 0, 0};
  gemm4_pre<128>(af4, wf1t, c0, f1a, li, lg, preF1);
  epi4(f1a, bf1, Hf, true, li, lg, q0, c0);

  bf16x8 preF2[4];
  pf_b1<128>(wf2t, c0, li, lg, preF2);
  bar();  // B6: Hf visible

  load_af128<4>(Hf, q0 + li, af4, lg);
  f32x4 f2a[4];
  #pragma unroll
  for (int i = 0; i < 4; ++i) f2a[i] = (f32x4){0, 0, 0, 0};
  gemm4_pre<128>(af4, wf2t, c0, f2a, li, lg, preF2);

  float* obase = out + (b * TT * NN + n) * DD;
  #pragma unroll
  for (int ct = 0; ct < 4; ++ct) {
    float bvv = bf2[c0 + ct * 16 + li];
    #pragma unroll
    for (int r = 0; r < 4; ++r)
      obase[(q0 + lg * 4 + r) * rs + c0 + ct * 16 + li] =
          x2r[ct][r] + fmaxf(f2a[ct][r] + bvv, 0.0f);
  }
  #undef SWZ256
}

extern "C" void kernel_launch(void* const* d_in, const int* in_sizes, int n_in,
                              void* d_out, int out_size, void* d_ws, size_t ws_size,
                              hipStream_t stream) {
  const float* x   = (const float*)d_in[0];
  const float* ste = (const float*)d_in[1];
  const float* g1 = (const float*)d_in[3];
  const float* b1 = (const float*)d_in[4];
  const float* g2 = (const float*)d_in[5];
  const float* b2 = (const float*)d_in[6];
  const float* Wq = (const float*)d_in[7];   const float* bq  = (const float*)d_in[8];
  const float* Wk = (const float*)d_in[9];   const float* bk  = (const float*)d_in[10];
  const float* Wv = (const float*)d_in[11];  const float* bv  = (const float*)d_in[12];
  const float* Wo1 = (const float*)d_in[13]; const float* bo1 = (const float*)d_in[14];
  const float* Wo2 = (const float*)d_in[15]; const float* bo2 = (const float*)d_in[16];
  const float* Wf1 = (const float*)d_in[17]; const float* bf1 = (const float*)d_in[18];
  const float* Wf2 = (const float*)d_in[19]; const float* bf2 = (const float*)d_in[20];
  float* out = (float*)d_out;

  unsigned short* wsu = (unsigned short*)d_ws;
  unsigned short* wq_t  = wsu;             // [128][256]
  unsigned short* wk_t  = wsu + 32768;
  unsigned short* wv_t  = wsu + 65536;
  unsigned short* wo1_t = wsu + 98304;     // [128][128]
  unsigned short* wo2_t = wsu + 114688;
  unsigned short* wf1_t = wsu + 131072;
  unsigned short* wf2_t = wsu + 147456;

  hipLaunchKernelGGL(wprep, dim3(128), dim3(256), 0, stream, Wq, wq_t, 256, 128);
  hipLaunchKernelGGL(wprep, dim3(128), dim3(256), 0, stream, Wk, wk_t, 256, 128);
  hipLaunchKernelGGL(wprep, dim3(128), dim3(256), 0, stream, Wv, wv_t, 256, 128);
  hipLaunchKernelGGL(wprep, dim3(64), dim3(256), 0, stream, Wo1, wo1_t, 128, 128);
  hipLaunchKernelGGL(wprep, dim3(64), dim3(256), 0, stream, Wo2, wo2_t, 128, 128);
  hipLaunchKernelGGL(wprep, dim3(64), dim3(256), 0, stream, Wf1, wf1_t, 128, 128);
  hipLaunchKernelGGL(wprep, dim3(64), dim3(256), 0, stream, Wf2, wf2_t, 128, 128);

  hipLaunchKernelGGL(fused_layer, dim3(8 * NN), dim3(512), 0, stream,
                     x, ste, g1, b1, g2, b2,
                     wq_t, bq, wk_t, bk, wv_t, bv,
                     wo1_t, bo1, wo2_t, bo2,
                     wf1_t, bf1, wf2_t, bf2, out);
}